// Round 10
// baseline (189.735 us; speedup 1.0000x reference)
//
#include <hip/hip_runtime.h>
#include <hip/hip_cooperative_groups.h>

namespace cg = cooperative_groups;

#define N_NODES 50000
#define DIM 64
#define NPB 64                                  // nodes per bucket (dst >> 6)
#define NB 782                                  // buckets = ceil(N/64)
#define NBLK 256                                // grid = 1 block per CU
#define TPB 1024                                // 16 waves per block
#define CAP 2048                                // aggregate LDS capacity (edges)

typedef unsigned short ushort_t;

__device__ __forceinline__ ushort_t f32_to_bf16(float f) {
    unsigned u = __float_as_uint(f);
    u += 0x7FFFu + ((u >> 16) & 1u);            // round-to-nearest-even
    return (ushort_t)(u >> 16);
}

__device__ __forceinline__ float bf16_to_f32(ushort_t h) {
    return __uint_as_float((unsigned)h << 16);
}

__global__ __launch_bounds__(TPB)
void fused_kernel(const float* __restrict__ xf,
                  ushort_t* __restrict__ xh,
                  const int* __restrict__ col,
                  const int* __restrict__ row,
                  int* __restrict__ localH,
                  int* __restrict__ bucket_total,
                  int* __restrict__ bucket_base,
                  unsigned* __restrict__ packed,
                  float* __restrict__ out,
                  int E, int chunkE, int n4) {
    cg::grid_group grid = cg::this_grid();

    __shared__ union {
        int h[NB];                              // A: hist, C: cursor
        int scanbuf[1024];                      // B3
        struct {                                // D
            unsigned buf[CAP];
            unsigned short srcs[CAP];
            int hist[NPB];
            int segoff[NPB];
            int cursor[NPB];
            int cnt[NPB];
        } d;
    } sm;

    const int bl = blockIdx.x;
    const int tid = threadIdx.x;
    const int lane = tid & 63;
    const int wv = tid >> 6;                    // wave 0..15

    // ================= Phase A: convert x->bf16 + per-chunk hist =================
    for (int i = bl * TPB + tid; i < n4; i += NBLK * TPB) {
        float4 v = *reinterpret_cast<const float4*>(xf + (size_t)i * 4);
        ushort4 hh;
        hh.x = f32_to_bf16(v.x);
        hh.y = f32_to_bf16(v.y);
        hh.z = f32_to_bf16(v.z);
        hh.w = f32_to_bf16(v.w);
        *reinterpret_cast<ushort4*>(xh + (size_t)i * 4) = hh;
    }
    for (int b = tid; b < NB; b += TPB) sm.h[b] = 0;
    __syncthreads();
    const int beg = bl * chunkE;
    const int end = min(beg + chunkE, E);
    if (end > beg) {
        int nfull = (end - beg) >> 2;
        for (int g = tid; g < nfull; g += TPB) {
            int4 c4 = *reinterpret_cast<const int4*>(col + beg + g * 4);
            atomicAdd(&sm.h[c4.x >> 6], 1);
            atomicAdd(&sm.h[c4.y >> 6], 1);
            atomicAdd(&sm.h[c4.z >> 6], 1);
            atomicAdd(&sm.h[c4.w >> 6], 1);
        }
        for (int e = beg + nfull * 4 + tid; e < end; e += TPB)
            atomicAdd(&sm.h[col[e] >> 6], 1);
    }
    __syncthreads();
    for (int b = tid; b < NB; b += TPB)
        localH[(size_t)bl * NB + b] = sm.h[b];

    grid.sync();

    // ===== Phase B2: per-bucket prefix over chunks (one wave per bucket) =====
    // localH[c][b] becomes the local (pre-base) start position; totals saved.
    {
        int wg = bl * 16 + wv;                  // global wave id
        if (wg < NB) {
            int b = wg;
            int running = 0;
            #pragma unroll
            for (int c0 = 0; c0 < NBLK; c0 += 64) {
                int c = c0 + lane;
                int v = localH[(size_t)c * NB + b];
                int incl = v;
                #pragma unroll
                for (int ofs = 1; ofs < 64; ofs <<= 1) {
                    int t = __shfl_up(incl, ofs);
                    if (lane >= ofs) incl += t;
                }
                localH[(size_t)c * NB + b] = running + incl - v;
                running += __shfl(incl, 63);
            }
            if (lane == 0) bucket_total[b] = running;
        }
    }

    grid.sync();

    // ============ Phase B3: block 0 scans bucket_total -> bucket_base ============
    if (bl == 0) {
        int v = (tid < NB) ? bucket_total[tid] : 0;
        sm.scanbuf[tid] = v;
        __syncthreads();
        for (int ofs = 1; ofs < 1024; ofs <<= 1) {
            int u = (tid >= ofs) ? sm.scanbuf[tid - ofs] : 0;
            __syncthreads();
            sm.scanbuf[tid] += u;
            __syncthreads();
        }
        if (tid < NB) bucket_base[tid] = sm.scanbuf[tid] - v;
        if (tid == NB - 1) bucket_base[NB] = sm.scanbuf[tid];
    }

    grid.sync();

    // ================= Phase C: binning scatter (LDS atomics only) =================
    for (int b = tid; b < NB; b += TPB)
        sm.h[b] = localH[(size_t)bl * NB + b] + bucket_base[b];
    __syncthreads();
    if (end > beg) {
        int nfull = (end - beg) >> 2;
        for (int g = tid; g < nfull; g += TPB) {
            int e = beg + g * 4;
            int4 d4 = *reinterpret_cast<const int4*>(col + e);
            int4 s4 = *reinterpret_cast<const int4*>(row + e);
            int p0 = atomicAdd(&sm.h[d4.x >> 6], 1);
            packed[p0] = (unsigned)s4.x | ((unsigned)(d4.x & 63) << 16);
            int p1 = atomicAdd(&sm.h[d4.y >> 6], 1);
            packed[p1] = (unsigned)s4.y | ((unsigned)(d4.y & 63) << 16);
            int p2 = atomicAdd(&sm.h[d4.z >> 6], 1);
            packed[p2] = (unsigned)s4.z | ((unsigned)(d4.z & 63) << 16);
            int p3 = atomicAdd(&sm.h[d4.w >> 6], 1);
            packed[p3] = (unsigned)s4.w | ((unsigned)(d4.w & 63) << 16);
        }
        for (int e = beg + nfull * 4 + tid; e < end; e += TPB) {
            int d = col[e];
            int p = atomicAdd(&sm.h[d >> 6], 1);
            packed[p] = (unsigned)row[e] | ((unsigned)(d & 63) << 16);
        }
    }

    grid.sync();

    // ========= Phase D: per-bucket counting sort + quarter-wave gather + mean =========
    // 16 waves; wave wv owns nodes [wv*4, wv*4+4). Quarter q gathers row j+q etc.
    const int q = lane >> 4;                    // quarter 0..3
    const int rr = lane & 15;                   // dim group (dims rr*4 .. rr*4+3)

    for (int b = bl; b < NB; b += NBLK) {
        int seg_beg = bucket_base[b];
        int seg_end = bucket_base[b + 1];
        int node_base = b * NPB;
        int nnodes = min(NPB, N_NODES - node_base);

        float4 acc[4];
        #pragma unroll
        for (int r = 0; r < 4; ++r) acc[r] = make_float4(0.f, 0.f, 0.f, 0.f);

        __syncthreads();                        // protect LDS reuse across buckets
        if (tid < NPB) sm.d.cnt[tid] = 0;

        for (int cs = seg_beg; cs < seg_end; cs += CAP) {
            int m = min(CAP, seg_end - cs);
            __syncthreads();
            if (tid < NPB) sm.d.hist[tid] = 0;
            __syncthreads();
            for (int i = tid; i < m; i += TPB) {
                unsigned v = packed[cs + i];
                sm.d.buf[i] = v;
                atomicAdd(&sm.d.hist[v >> 16], 1);
            }
            __syncthreads();
            if (tid < 64) {                     // wave 0: scan 64 bins
                int v = sm.d.hist[tid];
                int incl = v;
                #pragma unroll
                for (int ofs = 1; ofs < 64; ofs <<= 1) {
                    int t = __shfl_up(incl, ofs);
                    if (lane >= ofs) incl += t;
                }
                sm.d.segoff[tid] = incl - v;
                sm.d.cursor[tid] = incl - v;
                sm.d.cnt[tid] += v;
            }
            __syncthreads();
            for (int i = tid; i < m; i += TPB) {
                unsigned v = sm.d.buf[i];
                int p = atomicAdd(&sm.d.cursor[v >> 16], 1);
                sm.d.srcs[p] = (unsigned short)(v & 0xFFFF);
            }
            __syncthreads();
            #pragma unroll
            for (int r = 0; r < 4; ++r) {
                int ln = wv * 4 + r;
                int st = sm.d.segoff[ln];
                int len = sm.d.hist[ln];
                int j = 0;
                for (; j + 16 <= len; j += 16) {   // 16 rows in flight per wave
                    int s0 = sm.d.srcs[st + j + q];
                    int s1 = sm.d.srcs[st + j + 4 + q];
                    int s2 = sm.d.srcs[st + j + 8 + q];
                    int s3 = sm.d.srcs[st + j + 12 + q];
                    ushort4 h0 = *reinterpret_cast<const ushort4*>(xh + (size_t)s0 * DIM + rr * 4);
                    ushort4 h1 = *reinterpret_cast<const ushort4*>(xh + (size_t)s1 * DIM + rr * 4);
                    ushort4 h2 = *reinterpret_cast<const ushort4*>(xh + (size_t)s2 * DIM + rr * 4);
                    ushort4 h3 = *reinterpret_cast<const ushort4*>(xh + (size_t)s3 * DIM + rr * 4);
                    acc[r].x += bf16_to_f32(h0.x) + bf16_to_f32(h1.x) + bf16_to_f32(h2.x) + bf16_to_f32(h3.x);
                    acc[r].y += bf16_to_f32(h0.y) + bf16_to_f32(h1.y) + bf16_to_f32(h2.y) + bf16_to_f32(h3.y);
                    acc[r].z += bf16_to_f32(h0.z) + bf16_to_f32(h1.z) + bf16_to_f32(h2.z) + bf16_to_f32(h3.z);
                    acc[r].w += bf16_to_f32(h0.w) + bf16_to_f32(h1.w) + bf16_to_f32(h2.w) + bf16_to_f32(h3.w);
                }
                for (; j < len; j += 4) {
                    if (j + q < len) {
                        int s = sm.d.srcs[st + j + q];
                        ushort4 h0 = *reinterpret_cast<const ushort4*>(xh + (size_t)s * DIM + rr * 4);
                        acc[r].x += bf16_to_f32(h0.x);
                        acc[r].y += bf16_to_f32(h0.y);
                        acc[r].z += bf16_to_f32(h0.z);
                        acc[r].w += bf16_to_f32(h0.w);
                    }
                }
            }
        }
        __syncthreads();
        // cross-quarter reduce + mean + store
        #pragma unroll
        for (int r = 0; r < 4; ++r) {
            int ln = wv * 4 + r;
            float4 a = acc[r];
            a.x += __shfl_xor(a.x, 16); a.x += __shfl_xor(a.x, 32);
            a.y += __shfl_xor(a.y, 16); a.y += __shfl_xor(a.y, 32);
            a.z += __shfl_xor(a.z, 16); a.z += __shfl_xor(a.z, 32);
            a.w += __shfl_xor(a.w, 16); a.w += __shfl_xor(a.w, 32);
            if (q == 0 && ln < nnodes) {
                int c = sm.d.cnt[ln];
                float inv = (c > 0) ? 1.0f / (float)c : 0.0f;
                a.x *= inv; a.y *= inv; a.z *= inv; a.w *= inv;
                *reinterpret_cast<float4*>(out + (size_t)(node_base + ln) * DIM + rr * 4) = a;
            }
        }
    }
}

extern "C" void kernel_launch(void* const* d_in, const int* in_sizes, int n_in,
                              void* d_out, int out_size, void* d_ws, size_t ws_size,
                              hipStream_t stream) {
    const float* x = (const float*)d_in[0];
    const int* edge_index = (const int*)d_in[1];  // [2, E] flat: row then col
    int E = in_sizes[1] / 2;
    const int* row = edge_index;
    const int* col = edge_index + E;
    float* out = (float*)d_out;

    int chunkE = (((E + NBLK - 1) / NBLK) + 3) & ~3;    // multiple of 4
    int n4 = N_NODES * DIM / 4;

    // workspace: bucket_total 800 | bucket_base 800 | localH NBLK*NB | packed E | xh N*DIM bf16
    int* bucket_total = (int*)d_ws;
    int* bucket_base  = bucket_total + 800;
    int* localH       = bucket_base + 800;
    unsigned* packed  = (unsigned*)(localH + (size_t)NBLK * NB);
    ushort_t* xh      = (ushort_t*)(packed + E);

    void* args[] = {
        (void*)&x, (void*)&xh, (void*)&col, (void*)&row,
        (void*)&localH, (void*)&bucket_total, (void*)&bucket_base,
        (void*)&packed, (void*)&out, (void*)&E, (void*)&chunkE, (void*)&n4
    };
    hipLaunchCooperativeKernel((void*)fused_kernel, dim3(NBLK), dim3(TPB),
                               args, 0, stream);
}

// Round 11
// 62.306 us; speedup vs baseline: 3.0452x; 3.0452x over previous
//
#include <hip/hip_runtime.h>

#define N_NODES 50000
#define DIM 64
#define NPB 32                                  // nodes per bucket (dst >> 5)
#define NB 1563                                 // ceil(50000/32)
#define NCHUNK 128                              // edge chunks (= binning blocks)
#define CAP 1024                                // aggregate per-iteration LDS capacity

typedef unsigned short ushort_t;

__device__ __forceinline__ ushort_t f32_to_bf16(float f) {
    unsigned u = __float_as_uint(f);
    u += 0x7FFFu + ((u >> 16) & 1u);            // round-to-nearest-even
    return (ushort_t)(u >> 16);
}

__device__ __forceinline__ void acc_pair(float& a0, float& a1, unsigned u) {
    a0 += __uint_as_float(u << 16);             // low bf16  (even dim)
    a1 += __uint_as_float(u & 0xFFFF0000u);     // high bf16 (odd dim)
}

// ---- K1: fused convert(x->bf16) + per-chunk bucket histogram ----
__global__ void convert_hist_kernel(const float* __restrict__ xf,
                                    ushort_t* __restrict__ xh,
                                    const int* __restrict__ col,
                                    int* __restrict__ localH,
                                    int E, int chunk, int n4) {
    __shared__ int h[NB];
    int c = blockIdx.x;
    int tid = threadIdx.x;
    for (int i = c * blockDim.x + tid; i < n4; i += gridDim.x * blockDim.x) {
        float4 v = *reinterpret_cast<const float4*>(xf + (size_t)i * 4);
        ushort4 hh;
        hh.x = f32_to_bf16(v.x);
        hh.y = f32_to_bf16(v.y);
        hh.z = f32_to_bf16(v.z);
        hh.w = f32_to_bf16(v.w);
        *reinterpret_cast<ushort4*>(xh + (size_t)i * 4) = hh;
    }
    for (int b = tid; b < NB; b += blockDim.x) h[b] = 0;
    __syncthreads();
    int beg = c * chunk, end = min(beg + chunk, E);
    int nfull = (end - beg) >> 2;
    for (int g = tid; g < nfull; g += blockDim.x) {
        int4 c4 = *reinterpret_cast<const int4*>(col + beg + g * 4);
        atomicAdd(&h[c4.x >> 5], 1);
        atomicAdd(&h[c4.y >> 5], 1);
        atomicAdd(&h[c4.z >> 5], 1);
        atomicAdd(&h[c4.w >> 5], 1);
    }
    for (int e = beg + nfull * 4 + tid; e < end; e += blockDim.x)
        atomicAdd(&h[col[e] >> 5], 1);
    __syncthreads();
    for (int b = tid; b < NB; b += blockDim.x)
        localH[(size_t)c * NB + b] = h[b];
}

// ---- K2: per-bucket LOCAL prefix over chunks (in-place) + bucket totals ----
__global__ void chunk_offset_kernel(int* __restrict__ localH,
                                    int* __restrict__ bucket_total) {
    int b = blockIdx.x;
    int lane = threadIdx.x;                     // single wave per bucket
    int running = 0;
    #pragma unroll
    for (int c0 = 0; c0 < NCHUNK; c0 += 64) {
        int c = c0 + lane;
        int v = localH[(size_t)c * NB + b];
        int incl = v;
        #pragma unroll
        for (int ofs = 1; ofs < 64; ofs <<= 1) {
            int t = __shfl_up(incl, ofs);
            if (lane >= ofs) incl += t;
        }
        localH[(size_t)c * NB + b] = running + incl - v;
        running += __shfl(incl, 63);
    }
    if (lane == 0) bucket_total[b] = running;
}

// ---- K3: scan of bucket totals (2 buckets/thread) -> bucket_base[0..NB] ----
__global__ void total_scan_kernel(const int* __restrict__ bucket_total,
                                  int* __restrict__ bucket_base) {
    __shared__ int sm[1024];
    int t = threadIdx.x;
    int b0 = 2 * t, b1 = 2 * t + 1;
    int v0 = (b0 < NB) ? bucket_total[b0] : 0;
    int v1 = (b1 < NB) ? bucket_total[b1] : 0;
    int s = v0 + v1;
    sm[t] = s;
    __syncthreads();
    for (int ofs = 1; ofs < 1024; ofs <<= 1) {
        int u = (t >= ofs) ? sm[t - ofs] : 0;
        __syncthreads();
        sm[t] += u;
        __syncthreads();
    }
    int excl = sm[t] - s;
    if (b0 < NB) bucket_base[b0] = excl;
    if (b1 < NB) bucket_base[b1] = excl + v0;
    if (t == 1023) bucket_base[NB] = sm[t];     // grand total
}

// ---- K4: binning scatter — LDS atomics only; block-exclusive regions ----
__global__ void binning_kernel(const int* __restrict__ row,
                               const int* __restrict__ col,
                               const int* __restrict__ localH,
                               const int* __restrict__ bucket_base,
                               unsigned* __restrict__ packed,
                               int E, int chunk) {
    __shared__ int cursor[NB];
    int c = blockIdx.x;
    int tid = threadIdx.x;
    for (int b = tid; b < NB; b += blockDim.x)
        cursor[b] = localH[(size_t)c * NB + b] + bucket_base[b];
    __syncthreads();
    int beg = c * chunk, end = min(beg + chunk, E);
    int nfull = (end - beg) >> 2;
    for (int g = tid; g < nfull; g += blockDim.x) {
        int e = beg + g * 4;
        int4 d4 = *reinterpret_cast<const int4*>(col + e);
        int4 s4 = *reinterpret_cast<const int4*>(row + e);
        int p0 = atomicAdd(&cursor[d4.x >> 5], 1);
        packed[p0] = (unsigned)s4.x | ((unsigned)(d4.x & 31) << 16);
        int p1 = atomicAdd(&cursor[d4.y >> 5], 1);
        packed[p1] = (unsigned)s4.y | ((unsigned)(d4.y & 31) << 16);
        int p2 = atomicAdd(&cursor[d4.z >> 5], 1);
        packed[p2] = (unsigned)s4.z | ((unsigned)(d4.z & 31) << 16);
        int p3 = atomicAdd(&cursor[d4.w >> 5], 1);
        packed[p3] = (unsigned)s4.w | ((unsigned)(d4.w & 31) << 16);
    }
    for (int e = beg + nfull * 4 + tid; e < end; e += blockDim.x) {
        int d = col[e];
        int p = atomicAdd(&cursor[d >> 5], 1);
        packed[p] = (unsigned)row[e] | ((unsigned)(d & 31) << 16);
    }
}

// ---- K5: per-bucket counting sort (LDS) + 8-lane/row gather + mean ----
// 512 threads = 8 waves; wave wv owns nodes [wv*4, wv*4+4).
// Lane split: g8 = lane>>3 (row slot 0..7), o = lane&7 (dim octet).
// One uint4 load = 8 bf16 dims of one row; 8 rows per instruction per wave.
template <bool BF16>
__global__ __launch_bounds__(512)
void aggregate_bucket_kernel(const float* __restrict__ xf,
                             const ushort_t* __restrict__ xh,
                             const unsigned* __restrict__ packed,
                             const int* __restrict__ bucket_base,
                             float* __restrict__ out) {
    __shared__ unsigned buf[CAP];
    __shared__ unsigned short srcs[CAP];
    __shared__ int hist[NPB];
    __shared__ int segoff[NPB];
    __shared__ int cursor[NPB];
    __shared__ int cnt_tot[NPB];

    int b = blockIdx.x;
    int tid = threadIdx.x;                      // 0..511
    int lane = tid & 63;
    int wv = tid >> 6;                          // wave 0..7
    int g8 = lane >> 3;                         // row slot 0..7
    int o = lane & 7;                           // dim octet (dims o*8 .. o*8+7)
    int seg_beg = bucket_base[b];
    int seg_end = bucket_base[b + 1];
    int node_base = b * NPB;
    int nnodes = min(NPB, N_NODES - node_base);

    float acc[4][8];
    #pragma unroll
    for (int r = 0; r < 4; ++r)
        #pragma unroll
        for (int k = 0; k < 8; ++k) acc[r][k] = 0.0f;
    if (tid < NPB) cnt_tot[tid] = 0;

    for (int cs = seg_beg; cs < seg_end; cs += CAP) {
        int m = min(CAP, seg_end - cs);
        __syncthreads();
        if (tid < NPB) hist[tid] = 0;
        __syncthreads();
        for (int i = tid; i < m; i += 512) {
            unsigned v = packed[cs + i];
            buf[i] = v;
            atomicAdd(&hist[v >> 16], 1);
        }
        __syncthreads();
        if (tid < NPB) {                        // lanes 0..31 of wave 0: scan 32 bins
            int v = hist[tid];
            int incl = v;
            #pragma unroll
            for (int ofs = 1; ofs < 32; ofs <<= 1) {
                int t = __shfl_up(incl, ofs);
                if (lane >= ofs) incl += t;
            }
            segoff[tid] = incl - v;
            cursor[tid] = incl - v;
            cnt_tot[tid] += v;
        }
        __syncthreads();
        for (int i = tid; i < m; i += 512) {
            unsigned v = buf[i];
            int p = atomicAdd(&cursor[v >> 16], 1);
            srcs[p] = (unsigned short)(v & 0xFFFF);
        }
        __syncthreads();
        #pragma unroll
        for (int r = 0; r < 4; ++r) {
            int ln = wv * 4 + r;
            int st = segoff[ln];
            int len = hist[ln];
            int j = 0;
            for (; j + 16 <= len; j += 16) {    // 16 rows in flight per wave
                int s0 = srcs[st + j + g8];
                int s1 = srcs[st + j + 8 + g8];
                if (BF16) {
                    uint4 a0 = *reinterpret_cast<const uint4*>(xh + (size_t)s0 * DIM + o * 8);
                    uint4 a1 = *reinterpret_cast<const uint4*>(xh + (size_t)s1 * DIM + o * 8);
                    acc_pair(acc[r][0], acc[r][1], a0.x);
                    acc_pair(acc[r][2], acc[r][3], a0.y);
                    acc_pair(acc[r][4], acc[r][5], a0.z);
                    acc_pair(acc[r][6], acc[r][7], a0.w);
                    acc_pair(acc[r][0], acc[r][1], a1.x);
                    acc_pair(acc[r][2], acc[r][3], a1.y);
                    acc_pair(acc[r][4], acc[r][5], a1.z);
                    acc_pair(acc[r][6], acc[r][7], a1.w);
                } else {
                    float4 u0 = *reinterpret_cast<const float4*>(xf + (size_t)s0 * DIM + o * 8);
                    float4 u1 = *reinterpret_cast<const float4*>(xf + (size_t)s0 * DIM + o * 8 + 4);
                    float4 u2 = *reinterpret_cast<const float4*>(xf + (size_t)s1 * DIM + o * 8);
                    float4 u3 = *reinterpret_cast<const float4*>(xf + (size_t)s1 * DIM + o * 8 + 4);
                    acc[r][0] += u0.x + u2.x; acc[r][1] += u0.y + u2.y;
                    acc[r][2] += u0.z + u2.z; acc[r][3] += u0.w + u2.w;
                    acc[r][4] += u1.x + u3.x; acc[r][5] += u1.y + u3.y;
                    acc[r][6] += u1.z + u3.z; acc[r][7] += u1.w + u3.w;
                }
            }
            for (; j < len; j += 8) {
                if (j + g8 < len) {
                    int s = srcs[st + j + g8];
                    if (BF16) {
                        uint4 a0 = *reinterpret_cast<const uint4*>(xh + (size_t)s * DIM + o * 8);
                        acc_pair(acc[r][0], acc[r][1], a0.x);
                        acc_pair(acc[r][2], acc[r][3], a0.y);
                        acc_pair(acc[r][4], acc[r][5], a0.z);
                        acc_pair(acc[r][6], acc[r][7], a0.w);
                    } else {
                        float4 u0 = *reinterpret_cast<const float4*>(xf + (size_t)s * DIM + o * 8);
                        float4 u1 = *reinterpret_cast<const float4*>(xf + (size_t)s * DIM + o * 8 + 4);
                        acc[r][0] += u0.x; acc[r][1] += u0.y;
                        acc[r][2] += u0.z; acc[r][3] += u0.w;
                        acc[r][4] += u1.x; acc[r][5] += u1.y;
                        acc[r][6] += u1.z; acc[r][7] += u1.w;
                    }
                }
            }
        }
    }
    __syncthreads();
    // reduce across row slots (xor 8,16,32) + mean + store
    #pragma unroll
    for (int r = 0; r < 4; ++r) {
        int ln = wv * 4 + r;
        #pragma unroll
        for (int k = 0; k < 8; ++k) {
            acc[r][k] += __shfl_xor(acc[r][k], 8);
            acc[r][k] += __shfl_xor(acc[r][k], 16);
            acc[r][k] += __shfl_xor(acc[r][k], 32);
        }
        if (g8 == 0 && ln < nnodes) {
            int c = cnt_tot[ln];
            float inv = (c > 0) ? 1.0f / (float)c : 0.0f;
            float4 lo = make_float4(acc[r][0] * inv, acc[r][1] * inv,
                                    acc[r][2] * inv, acc[r][3] * inv);
            float4 hi = make_float4(acc[r][4] * inv, acc[r][5] * inv,
                                    acc[r][6] * inv, acc[r][7] * inv);
            float* op = out + (size_t)(node_base + ln) * DIM + o * 8;
            *reinterpret_cast<float4*>(op) = lo;
            *reinterpret_cast<float4*>(op + 4) = hi;
        }
    }
}

extern "C" void kernel_launch(void* const* d_in, const int* in_sizes, int n_in,
                              void* d_out, int out_size, void* d_ws, size_t ws_size,
                              hipStream_t stream) {
    const float* x = (const float*)d_in[0];
    const int* edge_index = (const int*)d_in[1];  // [2, E] flat: row then col
    int E = in_sizes[1] / 2;
    const int* row = edge_index;
    const int* col = edge_index + E;
    float* out = (float*)d_out;

    int chunk = (((E + NCHUNK - 1) / NCHUNK) + 3) & ~3;   // multiple of 4
    int n4 = N_NODES * DIM / 4;

    // ws: bucket_total 1568 | bucket_base 1568 | localH NCHUNK*NB | packed E | xh N*DIM bf16
    int* bucket_total = (int*)d_ws;
    int* bucket_base  = bucket_total + 1568;
    int* localH       = bucket_base + 1568;
    unsigned* packed  = (unsigned*)(localH + (size_t)NCHUNK * NB);
    ushort_t* xh      = (ushort_t*)(packed + E);
    size_t need_bf16  = (size_t)((char*)(xh + (size_t)N_NODES * DIM) - (char*)d_ws);
    bool use_bf16 = (ws_size >= need_bf16);

    convert_hist_kernel<<<NCHUNK, 1024, 0, stream>>>(x, xh, col, localH, E, chunk,
                                                     use_bf16 ? n4 : 0);
    chunk_offset_kernel<<<NB, 64, 0, stream>>>(localH, bucket_total);
    total_scan_kernel<<<1, 1024, 0, stream>>>(bucket_total, bucket_base);
    binning_kernel<<<NCHUNK, 1024, 0, stream>>>(row, col, localH, bucket_base,
                                                packed, E, chunk);
    if (use_bf16)
        aggregate_bucket_kernel<true><<<NB, 512, 0, stream>>>(x, xh, packed, bucket_base, out);
    else
        aggregate_bucket_kernel<false><<<NB, 512, 0, stream>>>(x, xh, packed, bucket_base, out);
}